// Round 18
// baseline (2503.697 us; speedup 1.0000x reference)
//
#include <hip/hip_runtime.h>
#include <hip/hip_bf16.h>

#define T_STEPS 512
#define D_IN 75
#define H_DIM 512
#define G_DIM 2048
#define NCLS_ 11
#define NKK 19           // 16 h-ktiles + 3 x-ktiles (K = 512 + 96pad = 608)
#define NGRP 16          // row-groups of 16 rows
#define NJ 16            // col-blocks per group (32 h-cols each)
#define CH_STRIDE 1536   // stamped chunk: 3 words x 512B (64 lanes x 8B)

typedef __attribute__((ext_vector_type(8))) short short8;
typedef __attribute__((ext_vector_type(4))) float f32x4;
typedef __attribute__((ext_vector_type(4))) unsigned int u32x4;

__device__ __forceinline__ unsigned short f2b(float f) {
  unsigned int u = __float_as_uint(f);
  unsigned int r = (u + 0x7fffu + ((u >> 16) & 1u)) >> 16;
  return (unsigned short)r;
}
__device__ __forceinline__ float b2f(unsigned short u) {
  return __uint_as_float(((unsigned int)u) << 16);
}
__device__ __forceinline__ float softplusf(float v) {
  return (v > 20.f) ? v : log1pf(__expf(v));
}
__device__ __forceinline__ float sigmf(float v) {
  return 1.f / (1.f + __expf(-v));
}
__device__ __forceinline__ float tanhf_(float v) {
  float a = fabsf(v);
  float e = __expf(-2.f * a);
  float r = (1.f - e) / (1.f + e);
  return copysignf(r, v);
}
__device__ __forceinline__ unsigned long long pack4(const unsigned short* v) {
  return (unsigned long long)v[0] | ((unsigned long long)v[1] << 16) |
         ((unsigned long long)v[2] << 32) | ((unsigned long long)v[3] << 48);
}

#define ALD(p) __hip_atomic_load((p), __ATOMIC_RELAXED, __HIP_MEMORY_SCOPE_AGENT)
#define AST(p, v) __hip_atomic_store((p), (v), __ATOMIC_RELAXED, __HIP_MEMORY_SCOPE_AGENT)

// ---------------------------------------------------------------------------
// Prologue 1: sample W = mu + softplus(rho)*eps for [w_hh; w_ih; 0pad]
// (608x2048), pack into MFMA B-fragment chunks. (Unchanged since round 1.)
// ---------------------------------------------------------------------------
__global__ __launch_bounds__(64) void pack_w_kernel(
    const float* __restrict__ wih_mu, const float* __restrict__ wih_rho, const float* __restrict__ eps_ih,
    const float* __restrict__ whh_mu, const float* __restrict__ whh_rho, const float* __restrict__ eps_hh,
    unsigned short* __restrict__ wpack)
{
  int c = blockIdx.x;             // 0..2431
  int j = c / (8 * NKK);
  int r = c % (8 * NKK);
  int wv = r / NKK;
  int kk = r % NKK;
  int l = threadIdx.x;
  int s = l & 15, grp = l >> 4;
  int q = s >> 2, cc = s & 3;
  int n = q * 512 + j * 32 + wv * 4 + cc;
  unsigned short vs[8];
#pragma unroll
  for (int e = 0; e < 8; ++e) {
    int k = kk * 32 + grp * 8 + e;
    float val = 0.f;
    if (k < 512) {
      int idx = k * G_DIM + n;
      val = whh_mu[idx] + softplusf(whh_rho[idx]) * eps_hh[idx];
    } else if (k < 512 + D_IN) {
      int idx = (k - 512) * G_DIM + n;
      val = wih_mu[idx] + softplusf(wih_rho[idx]) * eps_ih[idx];
    }
    vs[e] = f2b(val);
  }
  unsigned long long u0 = pack4(vs);
  unsigned long long u1 = pack4(vs + 4);
  unsigned long long* dst = (unsigned long long*)wpack + (size_t)c * 128 + l * 2;
  dst[0] = u0;
  dst[1] = u1;
}

// ---------------------------------------------------------------------------
// Prologue 2: pre-pack x into bf16 A-fragment layout. (Unchanged, round 11.)
// frag f = (t*8+g32)*6 + rg*3 + kx, g32 = 32-row group, rg = 16-row half.
// ---------------------------------------------------------------------------
__global__ __launch_bounds__(64) void pack_x_kernel(
    const float* __restrict__ x, unsigned short* __restrict__ xpack)
{
  int c = blockIdx.x;             // t*8 + g32, 0..4095
  int t = c >> 3, g = c & 7;
  int lane = threadIdx.x;
  int srow = lane & 15, grp = lane >> 4;
#pragma unroll
  for (int rg = 0; rg < 2; ++rg) {
    const float* xr = x + (size_t)(g * 32 + rg * 16 + srow) * (T_STEPS * D_IN) + (size_t)t * D_IN;
#pragma unroll
    for (int kx = 0; kx < 3; ++kx) {
      unsigned short vs[8];
#pragma unroll
      for (int e = 0; e < 8; ++e) {
        int d = kx * 32 + grp * 8 + e;
        vs[e] = f2b(d < D_IN ? xr[d] : 0.f);
      }
      unsigned long long* dp = (unsigned long long*)xpack +
          ((size_t)(c * 6 + rg * 3 + kx) * 64 + lane) * 2;
      dp[0] = pack4(vs);
      dp[1] = pack4(vs + 4);
    }
  }
}

// ---------------------------------------------------------------------------
// Persistent scan — round-17 geometry (256 blocks x 4 waves, 16-row groups,
// 16 col-blocks) with WAVE-AUTONOMOUS steps (no in-loop __syncthreads):
//   Each wave polls ALL 16 chunks itself (48 stamped words -> registers).
//   Data arrives in the detect round -> MFMA A-frags built in-register; the
//   LDS hstage, its ds_write/ds_read, and the block barrier are DELETED.
//   Removes the max-over-4-waves barrier jitter + the LDS staging hop from
//   the serial chain. Epilogue transpose stays wave-private (gatesT[w]).
// Safety: stamp t on EVERY position of every chunk proves every producer
// WAVE captured step t-1 from the opposite parity before publishing t
// (per-wave publish-after-detect), so the parity overwrite argument holds
// with no barrier. Stamps travel atomically with data (8B words).
// Protocol/format/replay-safety identical to round 17.
// ---------------------------------------------------------------------------
struct __align__(16) SmemLoop {
  float gatesT[4][2][16][20];          // 10KB [wave][ct][slotN][rowM pad20]
  unsigned short hq[4][16][8];         // 1KB  [wave][row][e] (16B rows)
};
union Smem {
  SmemLoop s;
  unsigned short zbuf[16][512];        // 16KB (post-loop FC only)
};

template <bool XP>
__global__ __launch_bounds__(256, 1) void lstm_scan_kernel(
    const float* __restrict__ x,
    const unsigned short* __restrict__ wpack,
    const unsigned short* __restrict__ xpack,
    const float* __restrict__ b_mu, const float* __restrict__ b_rho, const float* __restrict__ eps_b,
    const float* __restrict__ fc_w, const float* __restrict__ fc_b,
    char* __restrict__ hbuf, float* __restrict__ out)
{
  __shared__ Smem sm;

  const int bid = blockIdx.x;
  const int g8 = bid & 7;                 // XCD
  const int p = (bid >> 3) & 1;           // 16-row half within the 32-row set
  const int j = bid >> 4;                 // col-block 0..15
  const int gid = g8 * 2 + p;             // row-group 0..15
  const int tid = threadIdx.x;
  const int w = tid >> 6, lane = tid & 63;
  const int srow = lane & 15, grp = lane >> 4;

  // ---- stationary W fragments (2 ct x 19 ktiles x 16B per lane)
  short8 Wreg[2][NKK];
  {
    const short8* wp = (const short8*)wpack;
#pragma unroll
    for (int ct = 0; ct < 2; ++ct) {
      const int cj = (j * 8 + w * 2 + ct) * NKK;
#pragma unroll
      for (int kk = 0; kk < NKK; ++kk)
        Wreg[ct][kk] = wp[(size_t)(cj + kk) * 64 + lane];
    }
  }
  // ---- sampled bias (epilogue lane role: row=srow, cc=grp)
  float bias_[2][4];
#pragma unroll
  for (int ct = 0; ct < 2; ++ct)
#pragma unroll
    for (int q = 0; q < 4; ++q) {
      int idx = q * 512 + j * 32 + (w * 2 + ct) * 4 + grp;
      bias_[ct][q] = b_mu[idx] + softplusf(b_rho[idx]) * eps_b[idx];
    }

  float cst[2] = {0.f, 0.f};

  // ---- fallback path: per-wave x raw loads for t=0
  float xraw[3][8];
  if constexpr (!XP) {
    const float* xr = x + (size_t)(gid * 16 + srow) * (T_STEPS * D_IN);
#pragma unroll
    for (int kx = 0; kx < 3; ++kx)
#pragma unroll
      for (int e = 0; e < 8; ++e) {
        int d = kx * 32 + grp * 8 + e;
        xraw[kx][e] = (d < D_IN) ? xr[d] : 0.f;
      }
  }

  // ---- publish h_0 = 0, stamp 0 (all-zero words; tag 0 != 0xFFFF memset)
  {
    char* gp0 = hbuf + (size_t)(0 * NGRP + gid) * 16 * CH_STRIDE;
    if (lane < 16) {
      char* cb = gp0 + (size_t)j * CH_STRIDE + (size_t)(w * 16 + lane) * 8;
      AST((unsigned long long*)(cb), 0ull);
      AST((unsigned long long*)(cb + 512), 0ull);
      AST((unsigned long long*)(cb + 1024), 0ull);
    }
  }

  for (int t = 0; t < T_STEPS; ++t) {
    const int par = t & 1;
    short8 xf[3];

    // ---- XP: issue this step's 3 coalesced x-frag loads (cacheable; retire
    //      under the poll's first round — L2-hit latency)
    if constexpr (XP) {
      const short8* xp = (const short8*)xpack +
          ((size_t)((t * 8 + g8) * 6 + p * 3)) * 64 + lane;
#pragma unroll
      for (int kx = 0; kx < 3; ++kx)
        xf[kx] = xp[kx * 64];
    }

    // ---- poll-with-data: ALL 16 chunks x 3 stamped words (per wave)
    const char* gp = hbuf + (size_t)(par * NGRP + gid) * 16 * CH_STRIDE;
    unsigned long long pw[16][3];
    {
      const unsigned long long tgt = (unsigned long long)t;
      while (true) {
#pragma unroll
        for (int c16 = 0; c16 < 16; ++c16) {
          const char* cb = gp + (size_t)c16 * CH_STRIDE + (size_t)lane * 8;
          pw[c16][0] = ALD((const unsigned long long*)(cb));
          pw[c16][1] = ALD((const unsigned long long*)(cb + 512));
          pw[c16][2] = ALD((const unsigned long long*)(cb + 1024));
        }
        bool ok = true;
#pragma unroll
        for (int c16 = 0; c16 < 16; ++c16)
#pragma unroll
          for (int wd = 0; wd < 3; ++wd)
            ok &= ((pw[c16][wd] >> 48) == tgt);
        if (__all(ok)) break;
        __builtin_amdgcn_s_sleep(1);
      }
    }

    // ---- fallback: convert this step's x frags from raw regs
    if constexpr (!XP) {
#pragma unroll
      for (int kx = 0; kx < 3; ++kx) {
        unsigned short vs[8];
#pragma unroll
        for (int e = 0; e < 8; ++e) vs[e] = f2b(xraw[kx][e]);
        union { unsigned long long u[2]; short8 v; } q;
        q.u[0] = pack4(vs);
        q.u[1] = pack4(vs + 4);
        xf[kx] = q.v;
      }
    }

    // ---- fallback: issue x raw loads for t+1 (land during MFMA..next poll)
    if constexpr (!XP) {
      if (t + 1 < T_STEPS) {
        const float* xr = x + (size_t)(gid * 16 + srow) * (T_STEPS * D_IN) + (size_t)(t + 1) * D_IN;
#pragma unroll
        for (int kx = 0; kx < 3; ++kx)
#pragma unroll
          for (int e = 0; e < 8; ++e) {
            int d = kx * 32 + grp * 8 + e;
            xraw[kx][e] = (d < D_IN) ? xr[d] : 0.f;
          }
      }
    }

    // ---- MFMA directly from registers: 3 x-tiles + 16 h-tiles (no barrier,
    //      no LDS staging — A-frags built in-register from stamped words)
    f32x4 acc[2];
    acc[0] = (f32x4){0.f, 0.f, 0.f, 0.f};
    acc[1] = (f32x4){0.f, 0.f, 0.f, 0.f};
#pragma unroll
    for (int kx = 0; kx < 3; ++kx) {
      acc[0] = __builtin_amdgcn_mfma_f32_16x16x32_bf16(xf[kx], Wreg[0][16 + kx], acc[0], 0, 0, 0);
      acc[1] = __builtin_amdgcn_mfma_f32_16x16x32_bf16(xf[kx], Wreg[1][16 + kx], acc[1], 0, 0, 0);
    }
#pragma unroll
    for (int kk = 0; kk < 16; ++kk) {
      unsigned long long w0 = pw[kk][0], w1 = pw[kk][1], w2 = pw[kk][2];
      unsigned long long lo = (w0 & 0x0000FFFFFFFFFFFFull) | (w1 << 48);
      unsigned long long hi = ((w1 >> 16) & 0xFFFFFFFFull) | ((w2 & 0xFFFFFFFFull) << 32);
      union { unsigned long long u[2]; short8 v; } q;
      q.u[0] = lo;
      q.u[1] = hi;
      acc[0] = __builtin_amdgcn_mfma_f32_16x16x32_bf16(q.v, Wreg[0][kk], acc[0], 0, 0, 0);
      acc[1] = __builtin_amdgcn_mfma_f32_16x16x32_bf16(q.v, Wreg[1][kk], acc[1], 0, 0, 0);
    }

    // ---- epilogue: wave-private LDS transpose, activations, c/h update
#pragma unroll
    for (int ct = 0; ct < 2; ++ct)
      *(f32x4*)&sm.s.gatesT[w][ct][srow][grp * 4] = acc[ct];
#pragma unroll
    for (int ct = 0; ct < 2; ++ct) {
      float vi = sm.s.gatesT[w][ct][grp + 0][srow] + bias_[ct][0];
      float vf = sm.s.gatesT[w][ct][grp + 4][srow] + bias_[ct][1];
      float vg = sm.s.gatesT[w][ct][grp + 8][srow] + bias_[ct][2];
      float vo = sm.s.gatesT[w][ct][grp + 12][srow] + bias_[ct][3];
      float ii = sigmf(vi), ff = sigmf(vf);
      float gg = tanhf_(vg), oo = sigmf(vo);
      float cn = ff * cst[ct] + ii * gg;
      cst[ct] = cn;
      float hh = oo * tanhf_(cn);
      sm.s.hq[w][srow][ct * 4 + grp] = f2b(hh);
    }

    // ---- stamped publish (fire-and-forget: no ack, no flag, no barrier)
    {
      char* gpn = hbuf + (size_t)(((t + 1) & 1) * NGRP + gid) * 16 * CH_STRIDE;
      if (lane < 16) {
        const unsigned long long* hp = (const unsigned long long*)&sm.s.hq[w][lane][0];
        unsigned long long a = hp[0], b = hp[1];
        unsigned long long st = ((unsigned long long)(t + 1)) << 48;
        unsigned long long w0 = (a & 0x0000FFFFFFFFFFFFull) | st;
        unsigned long long w1 = ((a >> 48) | ((b & 0xFFFFFFFFull) << 16)) | st;
        unsigned long long w2 = ((b >> 32) & 0xFFFFFFFFull) | st;
        char* cb = gpn + (size_t)j * CH_STRIDE + (size_t)(w * 16 + lane) * 8;
        AST((unsigned long long*)(cb), w0);
        AST((unsigned long long*)(cb + 512), w1);
        AST((unsigned long long*)(cb + 1024), w2);
      }
    }
  }

  // ---- final FC: z = h_T @ fc_w^T + fc_b (j==0 blocks; h_T stamp 512, parity 0)
  if (j == 0) {
    __syncthreads();   // all waves past loop before zbuf overwrites gatesT
    const char* gp0 = hbuf + (size_t)(0 * NGRP + gid) * 16 * CH_STRIDE;
    unsigned long long pw[4][3];
    {
      const unsigned long long tgt = (unsigned long long)T_STEPS;
      while (true) {
#pragma unroll
        for (int c4 = 0; c4 < 4; ++c4) {
          const char* cb = gp0 + (size_t)(w * 4 + c4) * CH_STRIDE + (size_t)lane * 8;
          pw[c4][0] = ALD((const unsigned long long*)(cb));
          pw[c4][1] = ALD((const unsigned long long*)(cb + 512));
          pw[c4][2] = ALD((const unsigned long long*)(cb + 1024));
        }
        bool ok = true;
#pragma unroll
        for (int c4 = 0; c4 < 4; ++c4)
#pragma unroll
          for (int wd = 0; wd < 3; ++wd)
            ok &= ((pw[c4][wd] >> 48) == tgt);
        if (__all(ok)) break;
        __builtin_amdgcn_s_sleep(1);
      }
    }
#pragma unroll
    for (int c4 = 0; c4 < 4; ++c4) {
      unsigned long long w0 = pw[c4][0], w1 = pw[c4][1], w2 = pw[c4][2];
      unsigned long long lo = (w0 & 0x0000FFFFFFFFFFFFull) | (w1 << 48);
      unsigned long long hi = ((w1 >> 16) & 0xFFFFFFFFull) | ((w2 & 0xFFFFFFFFull) << 32);
      int kk = w * 4 + c4;
      int row = lane & 15, k0 = kk * 32 + (lane >> 4) * 8;
      union { unsigned long long u[2]; u32x4 q; } fq;
      fq.u[0] = lo;
      fq.u[1] = hi;
      *(u32x4*)&sm.zbuf[row][k0] = fq.q;
    }
    __syncthreads();
    for (int i = tid; i < 16 * NCLS_; i += 256) {
      int r = i / NCLS_, n = i % NCLS_;
      float s = fc_b[n];
      const float* fw = fc_w + n * H_DIM;
      for (int k = 0; k < H_DIM; ++k)
        s += b2f(sm.zbuf[r][k]) * fw[k];
      out[(gid * 16 + r) * NCLS_ + n] = s;
    }
  }
}

// ---------------------------------------------------------------------------
extern "C" void kernel_launch(void* const* d_in, const int* in_sizes, int n_in,
                              void* d_out, int out_size, void* d_ws, size_t ws_size,
                              hipStream_t stream) {
  const float* x       = (const float*)d_in[0];
  const float* wih_mu  = (const float*)d_in[1];
  const float* wih_rho = (const float*)d_in[2];
  const float* eps_ih  = (const float*)d_in[3];
  const float* whh_mu  = (const float*)d_in[4];
  const float* whh_rho = (const float*)d_in[5];
  const float* eps_hh  = (const float*)d_in[6];
  const float* b_mu    = (const float*)d_in[7];
  const float* b_rho   = (const float*)d_in[8];
  const float* eps_b   = (const float*)d_in[9];
  const float* fc_w    = (const float*)d_in[10];
  const float* fc_b    = (const float*)d_in[11];

  // ws layout: wpack [0, 2490368) | hbuf [2490368, +786432)
  //            xpack [3276800, +25165824)  (only if ws_size allows)
  unsigned short* wpack = (unsigned short*)d_ws;
  char* hbuf = (char*)d_ws + 2490368;
  unsigned short* xpack = (unsigned short*)((char*)d_ws + 3276800);
  const bool use_xpack = (ws_size >= 3276800ull + 25165824ull);

  // Clear ALL stamps each launch (replay safety): tag 0xFFFF matches no step.
  hipMemsetAsync(hbuf, 0xFF, 2 * NGRP * 16 * CH_STRIDE, stream);
  pack_w_kernel<<<NJ * 8 * NKK, 64, 0, stream>>>(wih_mu, wih_rho, eps_ih,
                                                 whh_mu, whh_rho, eps_hh, wpack);
  if (use_xpack) {
    pack_x_kernel<<<T_STEPS * 8, 64, 0, stream>>>(x, xpack);
    lstm_scan_kernel<true><<<NGRP * NJ, 256, 0, stream>>>(
        x, wpack, xpack, b_mu, b_rho, eps_b, fc_w, fc_b, hbuf, (float*)d_out);
  } else {
    lstm_scan_kernel<false><<<NGRP * NJ, 256, 0, stream>>>(
        x, wpack, (const unsigned short*)nullptr, b_mu, b_rho, eps_b,
        fc_w, fc_b, hbuf, (float*)d_out);
  }
}

// Round 19
// 1306.769 us; speedup vs baseline: 1.9159x; 1.9159x over previous
//
#include <hip/hip_runtime.h>
#include <hip/hip_bf16.h>

#define T_STEPS 512
#define D_IN 75
#define H_DIM 512
#define G_DIM 2048
#define NCLS_ 11
#define NKK 19           // 16 h-ktiles + 3 x-ktiles (K = 512 + 96pad = 608)
#define NGRP 16          // row-groups of 16 rows
#define NJ 16            // col-blocks per group (32 h-cols each)
#define CH_STRIDE 1536   // stamped chunk: 3 words x 512B (64 lanes x 8B)

typedef __attribute__((ext_vector_type(8))) short short8;
typedef __attribute__((ext_vector_type(4))) float f32x4;
typedef __attribute__((ext_vector_type(4))) unsigned int u32x4;

__device__ __forceinline__ unsigned short f2b(float f) {
  unsigned int u = __float_as_uint(f);
  unsigned int r = (u + 0x7fffu + ((u >> 16) & 1u)) >> 16;
  return (unsigned short)r;
}
__device__ __forceinline__ float b2f(unsigned short u) {
  return __uint_as_float(((unsigned int)u) << 16);
}
__device__ __forceinline__ float softplusf(float v) {
  return (v > 20.f) ? v : log1pf(__expf(v));
}
__device__ __forceinline__ float sigmf(float v) {
  return 1.f / (1.f + __expf(-v));
}
__device__ __forceinline__ float tanhf_(float v) {
  float a = fabsf(v);
  float e = __expf(-2.f * a);
  float r = (1.f - e) / (1.f + e);
  return copysignf(r, v);
}
__device__ __forceinline__ unsigned long long pack4(const unsigned short* v) {
  return (unsigned long long)v[0] | ((unsigned long long)v[1] << 16) |
         ((unsigned long long)v[2] << 32) | ((unsigned long long)v[3] << 48);
}

#define ALD(p) __hip_atomic_load((p), __ATOMIC_RELAXED, __HIP_MEMORY_SCOPE_AGENT)
#define AST(p, v) __hip_atomic_store((p), (v), __ATOMIC_RELAXED, __HIP_MEMORY_SCOPE_AGENT)

// ---------------------------------------------------------------------------
// Prologue 1: sample W = mu + softplus(rho)*eps for [w_hh; w_ih; 0pad]
// (608x2048), pack into MFMA B-fragment chunks. (Unchanged since round 1.)
// ---------------------------------------------------------------------------
__global__ __launch_bounds__(64) void pack_w_kernel(
    const float* __restrict__ wih_mu, const float* __restrict__ wih_rho, const float* __restrict__ eps_ih,
    const float* __restrict__ whh_mu, const float* __restrict__ whh_rho, const float* __restrict__ eps_hh,
    unsigned short* __restrict__ wpack)
{
  int c = blockIdx.x;             // 0..2431
  int j = c / (8 * NKK);
  int r = c % (8 * NKK);
  int wv = r / NKK;
  int kk = r % NKK;
  int l = threadIdx.x;
  int s = l & 15, grp = l >> 4;
  int q = s >> 2, cc = s & 3;
  int n = q * 512 + j * 32 + wv * 4 + cc;
  unsigned short vs[8];
#pragma unroll
  for (int e = 0; e < 8; ++e) {
    int k = kk * 32 + grp * 8 + e;
    float val = 0.f;
    if (k < 512) {
      int idx = k * G_DIM + n;
      val = whh_mu[idx] + softplusf(whh_rho[idx]) * eps_hh[idx];
    } else if (k < 512 + D_IN) {
      int idx = (k - 512) * G_DIM + n;
      val = wih_mu[idx] + softplusf(wih_rho[idx]) * eps_ih[idx];
    }
    vs[e] = f2b(val);
  }
  unsigned long long u0 = pack4(vs);
  unsigned long long u1 = pack4(vs + 4);
  unsigned long long* dst = (unsigned long long*)wpack + (size_t)c * 128 + l * 2;
  dst[0] = u0;
  dst[1] = u1;
}

// ---------------------------------------------------------------------------
// Prologue 2: pre-pack x into bf16 A-fragment layout. (Unchanged, round 11.)
// frag f = (t*8+g32)*6 + rg*3 + kx, g32 = 32-row group, rg = 16-row half.
// ---------------------------------------------------------------------------
__global__ __launch_bounds__(64) void pack_x_kernel(
    const float* __restrict__ x, unsigned short* __restrict__ xpack)
{
  int c = blockIdx.x;             // t*8 + g32, 0..4095
  int t = c >> 3, g = c & 7;
  int lane = threadIdx.x;
  int srow = lane & 15, grp = lane >> 4;
#pragma unroll
  for (int rg = 0; rg < 2; ++rg) {
    const float* xr = x + (size_t)(g * 32 + rg * 16 + srow) * (T_STEPS * D_IN) + (size_t)t * D_IN;
#pragma unroll
    for (int kx = 0; kx < 3; ++kx) {
      unsigned short vs[8];
#pragma unroll
      for (int e = 0; e < 8; ++e) {
        int d = kx * 32 + grp * 8 + e;
        vs[e] = f2b(d < D_IN ? xr[d] : 0.f);
      }
      unsigned long long* dp = (unsigned long long*)xpack +
          ((size_t)(c * 6 + rg * 3 + kx) * 64 + lane) * 2;
      dp[0] = pack4(vs);
      dp[1] = pack4(vs + 4);
    }
  }
}

// ---------------------------------------------------------------------------
// Persistent scan — round-17 (session best, 1313us): round-15 PROTOCOL
// (stamped 8B words, full-burst poll-with-data, batched full-reload retry,
// parity double-buffered hstage, fire-and-forget publish, memset-0xFF replay
// safety) with halved per-block compute on 2x the blocks:
//   256 blocks x 4 waves. g8 = bid&7 (XCD), p = (bid>>3)&1, j = bid>>4.
//   Group gid = g8*2+p: rows gid*16..+15 (ONE rg), 16 col-blocks on one XCD.
//   Wave w: cols j*32 + (w*2+ct)*4+grp; polls/stages 4 chunks (12 words);
//   38 MFMAs; wave-private epilogue; per-wave publish.
// Round-18's wave-autonomous variant (all 16 chunks per wave, no barrier)
// REVERTED: VGPR 120->192 + 4x poll traffic regressed 1313->2504us.
// This kernel is latency-bound on the inter-block h exchange (~6150 cy/step);
// MfmaUtil 10%, HBM 3.3% — far from compute/BW rooflines, at the measured
// floor of this sync-protocol family (rounds 9,12,13,14,16,18 all regressed).
// ---------------------------------------------------------------------------
struct __align__(16) SmemLoop {
  unsigned short hstage[2][16][64][8]; // 32KB [parity][chunk][lane][e]
  float gatesT[4][2][16][20];          // 10KB [wave][ct][slotN][rowM pad20]
  unsigned short hq[4][16][8];         // 1KB  [wave][row][e] (16B rows)
};
union Smem {
  SmemLoop s;
  unsigned short zbuf[16][512];        // 16KB (post-loop FC only)
};

template <bool XP>
__global__ __launch_bounds__(256, 1) void lstm_scan_kernel(
    const float* __restrict__ x,
    const unsigned short* __restrict__ wpack,
    const unsigned short* __restrict__ xpack,
    const float* __restrict__ b_mu, const float* __restrict__ b_rho, const float* __restrict__ eps_b,
    const float* __restrict__ fc_w, const float* __restrict__ fc_b,
    char* __restrict__ hbuf, float* __restrict__ out)
{
  __shared__ Smem sm;

  const int bid = blockIdx.x;
  const int g8 = bid & 7;                 // XCD
  const int p = (bid >> 3) & 1;           // 16-row half within the 32-row set
  const int j = bid >> 4;                 // col-block 0..15
  const int gid = g8 * 2 + p;             // row-group 0..15
  const int tid = threadIdx.x;
  const int w = tid >> 6, lane = tid & 63;
  const int srow = lane & 15, grp = lane >> 4;

  // ---- stationary W fragments (2 ct x 19 ktiles x 16B per lane)
  short8 Wreg[2][NKK];
  {
    const short8* wp = (const short8*)wpack;
#pragma unroll
    for (int ct = 0; ct < 2; ++ct) {
      const int cj = (j * 8 + w * 2 + ct) * NKK;
#pragma unroll
      for (int kk = 0; kk < NKK; ++kk)
        Wreg[ct][kk] = wp[(size_t)(cj + kk) * 64 + lane];
    }
  }
  // ---- sampled bias (epilogue lane role: row=srow, cc=grp)
  float bias_[2][4];
#pragma unroll
  for (int ct = 0; ct < 2; ++ct)
#pragma unroll
    for (int q = 0; q < 4; ++q) {
      int idx = q * 512 + j * 32 + (w * 2 + ct) * 4 + grp;
      bias_[ct][q] = b_mu[idx] + softplusf(b_rho[idx]) * eps_b[idx];
    }

  float cst[2] = {0.f, 0.f};

  // ---- fallback path: per-wave x raw loads for t=0
  float xraw[3][8];
  if constexpr (!XP) {
    const float* xr = x + (size_t)(gid * 16 + srow) * (T_STEPS * D_IN);
#pragma unroll
    for (int kx = 0; kx < 3; ++kx)
#pragma unroll
      for (int e = 0; e < 8; ++e) {
        int d = kx * 32 + grp * 8 + e;
        xraw[kx][e] = (d < D_IN) ? xr[d] : 0.f;
      }
  }

  // ---- publish h_0 = 0, stamp 0 (all-zero words; tag 0 != 0xFFFF memset)
  {
    char* gp0 = hbuf + (size_t)(0 * NGRP + gid) * 16 * CH_STRIDE;
    if (lane < 16) {
      char* cb = gp0 + (size_t)j * CH_STRIDE + (size_t)(w * 16 + lane) * 8;
      AST((unsigned long long*)(cb), 0ull);
      AST((unsigned long long*)(cb + 512), 0ull);
      AST((unsigned long long*)(cb + 1024), 0ull);
    }
  }

  for (int t = 0; t < T_STEPS; ++t) {
    const int par = t & 1;
    short8 xf[3];

    // ---- XP: issue this step's 3 coalesced x-frag loads (cacheable; retire
    //      under the poll's first round — L2-hit latency)
    if constexpr (XP) {
      const short8* xp = (const short8*)xpack +
          ((size_t)((t * 8 + g8) * 6 + p * 3)) * 64 + lane;
#pragma unroll
      for (int kx = 0; kx < 3; ++kx)
        xf[kx] = xp[kx * 64];
    }

    // ---- poll-with-data: this wave's 4 chunks x 3 stamped words
    const char* gp = hbuf + (size_t)(par * NGRP + gid) * 16 * CH_STRIDE;
    unsigned long long pw[4][3];
    {
      const unsigned long long tgt = (unsigned long long)t;
      while (true) {
#pragma unroll
        for (int c4 = 0; c4 < 4; ++c4) {
          const char* cb = gp + (size_t)(w * 4 + c4) * CH_STRIDE + (size_t)lane * 8;
          pw[c4][0] = ALD((const unsigned long long*)(cb));
          pw[c4][1] = ALD((const unsigned long long*)(cb + 512));
          pw[c4][2] = ALD((const unsigned long long*)(cb + 1024));
        }
        bool ok = true;
#pragma unroll
        for (int c4 = 0; c4 < 4; ++c4)
#pragma unroll
          for (int wd = 0; wd < 3; ++wd)
            ok &= ((pw[c4][wd] >> 48) == tgt);
        if (__all(ok)) break;
        __builtin_amdgcn_s_sleep(1);
      }
    }

    // ---- fallback: convert this step's x frags from raw regs
    if constexpr (!XP) {
#pragma unroll
      for (int kx = 0; kx < 3; ++kx) {
        unsigned short vs[8];
#pragma unroll
        for (int e = 0; e < 8; ++e) vs[e] = f2b(xraw[kx][e]);
        union { unsigned long long u[2]; short8 v; } q;
        q.u[0] = pack4(vs);
        q.u[1] = pack4(vs + 4);
        xf[kx] = q.v;
      }
    }

    // ---- extract stamped words -> A-frag 16B, ds_write b128 (conflict-free)
#pragma unroll
    for (int c4 = 0; c4 < 4; ++c4) {
      unsigned long long w0 = pw[c4][0], w1 = pw[c4][1], w2 = pw[c4][2];
      unsigned long long lo = (w0 & 0x0000FFFFFFFFFFFFull) | (w1 << 48);
      unsigned long long hi = ((w1 >> 16) & 0xFFFFFFFFull) | ((w2 & 0xFFFFFFFFull) << 32);
      union { unsigned long long u[2]; u32x4 q; } fq;
      fq.u[0] = lo;
      fq.u[1] = hi;
      *(u32x4*)&sm.s.hstage[par][w * 4 + c4][lane][0] = fq.q;
    }

    // ---- fallback: issue x raw loads for t+1 (land during MFMA..next poll)
    if constexpr (!XP) {
      if (t + 1 < T_STEPS) {
        const float* xr = x + (size_t)(gid * 16 + srow) * (T_STEPS * D_IN) + (size_t)(t + 1) * D_IN;
#pragma unroll
        for (int kx = 0; kx < 3; ++kx)
#pragma unroll
          for (int e = 0; e < 8; ++e) {
            int d = kx * 32 + grp * 8 + e;
            xraw[kx][e] = (d < D_IN) ? xr[d] : 0.f;
          }
      }
    }

    __syncthreads();   // hstage[par] complete

    // ---- MFMA: 3 x-tiles (reg frags) + 16 h-tiles (LDS), 2 ct each
    f32x4 acc[2];
    acc[0] = (f32x4){0.f, 0.f, 0.f, 0.f};
    acc[1] = (f32x4){0.f, 0.f, 0.f, 0.f};
#pragma unroll
    for (int kx = 0; kx < 3; ++kx) {
      acc[0] = __builtin_amdgcn_mfma_f32_16x16x32_bf16(xf[kx], Wreg[0][16 + kx], acc[0], 0, 0, 0);
      acc[1] = __builtin_amdgcn_mfma_f32_16x16x32_bf16(xf[kx], Wreg[1][16 + kx], acc[1], 0, 0, 0);
    }
#pragma unroll
    for (int kk = 0; kk < 16; ++kk) {
      short8 a = *(const short8*)&sm.s.hstage[par][kk][lane][0];
      acc[0] = __builtin_amdgcn_mfma_f32_16x16x32_bf16(a, Wreg[0][kk], acc[0], 0, 0, 0);
      acc[1] = __builtin_amdgcn_mfma_f32_16x16x32_bf16(a, Wreg[1][kk], acc[1], 0, 0, 0);
    }

    // ---- epilogue: in-wave LDS transpose, activations, c/h update
#pragma unroll
    for (int ct = 0; ct < 2; ++ct)
      *(f32x4*)&sm.s.gatesT[w][ct][srow][grp * 4] = acc[ct];
#pragma unroll
    for (int ct = 0; ct < 2; ++ct) {
      float vi = sm.s.gatesT[w][ct][grp + 0][srow] + bias_[ct][0];
      float vf = sm.s.gatesT[w][ct][grp + 4][srow] + bias_[ct][1];
      float vg = sm.s.gatesT[w][ct][grp + 8][srow] + bias_[ct][2];
      float vo = sm.s.gatesT[w][ct][grp + 12][srow] + bias_[ct][3];
      float ii = sigmf(vi), ff = sigmf(vf);
      float gg = tanhf_(vg), oo = sigmf(vo);
      float cn = ff * cst[ct] + ii * gg;
      cst[ct] = cn;
      float hh = oo * tanhf_(cn);
      sm.s.hq[w][srow][ct * 4 + grp] = f2b(hh);
    }

    // ---- stamped publish (fire-and-forget: no ack, no flag)
    {
      char* gpn = hbuf + (size_t)(((t + 1) & 1) * NGRP + gid) * 16 * CH_STRIDE;
      if (lane < 16) {
        const unsigned long long* hp = (const unsigned long long*)&sm.s.hq[w][lane][0];
        unsigned long long a = hp[0], b = hp[1];
        unsigned long long st = ((unsigned long long)(t + 1)) << 48;
        unsigned long long w0 = (a & 0x0000FFFFFFFFFFFFull) | st;
        unsigned long long w1 = ((a >> 48) | ((b & 0xFFFFFFFFull) << 16)) | st;
        unsigned long long w2 = ((b >> 32) & 0xFFFFFFFFull) | st;
        char* cb = gpn + (size_t)j * CH_STRIDE + (size_t)(w * 16 + lane) * 8;
        AST((unsigned long long*)(cb), w0);
        AST((unsigned long long*)(cb + 512), w1);
        AST((unsigned long long*)(cb + 1024), w2);
      }
    }
  }

  // ---- final FC: z = h_T @ fc_w^T + fc_b (j==0 blocks; h_T stamp 512, parity 0)
  if (j == 0) {
    __syncthreads();   // all waves past loop before zbuf overwrites hstage
    const char* gp0 = hbuf + (size_t)(0 * NGRP + gid) * 16 * CH_STRIDE;
    unsigned long long pw[4][3];
    {
      const unsigned long long tgt = (unsigned long long)T_STEPS;
      while (true) {
#pragma unroll
        for (int c4 = 0; c4 < 4; ++c4) {
          const char* cb = gp0 + (size_t)(w * 4 + c4) * CH_STRIDE + (size_t)lane * 8;
          pw[c4][0] = ALD((const unsigned long long*)(cb));
          pw[c4][1] = ALD((const unsigned long long*)(cb + 512));
          pw[c4][2] = ALD((const unsigned long long*)(cb + 1024));
        }
        bool ok = true;
#pragma unroll
        for (int c4 = 0; c4 < 4; ++c4)
#pragma unroll
          for (int wd = 0; wd < 3; ++wd)
            ok &= ((pw[c4][wd] >> 48) == tgt);
        if (__all(ok)) break;
        __builtin_amdgcn_s_sleep(1);
      }
    }
#pragma unroll
    for (int c4 = 0; c4 < 4; ++c4) {
      unsigned long long w0 = pw[c4][0], w1 = pw[c4][1], w2 = pw[c4][2];
      unsigned long long lo = (w0 & 0x0000FFFFFFFFFFFFull) | (w1 << 48);
      unsigned long long hi = ((w1 >> 16) & 0xFFFFFFFFull) | ((w2 & 0xFFFFFFFFull) << 32);
      int kk = w * 4 + c4;
      int row = lane & 15, k0 = kk * 32 + (lane >> 4) * 8;
      union { unsigned long long u[2]; u32x4 q; } fq;
      fq.u[0] = lo;
      fq.u[1] = hi;
      *(u32x4*)&sm.zbuf[row][k0] = fq.q;
    }
    __syncthreads();
    for (int i = tid; i < 16 * NCLS_; i += 256) {
      int r = i / NCLS_, n = i % NCLS_;
      float s = fc_b[n];
      const float* fw = fc_w + n * H_DIM;
      for (int k = 0; k < H_DIM; ++k)
        s += b2f(sm.zbuf[r][k]) * fw[k];
      out[(gid * 16 + r) * NCLS_ + n] = s;
    }
  }
}

// ---------------------------------------------------------------------------
extern "C" void kernel_launch(void* const* d_in, const int* in_sizes, int n_in,
                              void* d_out, int out_size, void* d_ws, size_t ws_size,
                              hipStream_t stream) {
  const float* x       = (const float*)d_in[0];
  const float* wih_mu  = (const float*)d_in[1];
  const float* wih_rho = (const float*)d_in[2];
  const float* eps_ih  = (const float*)d_in[3];
  const float* whh_mu  = (const float*)d_in[4];
  const float* whh_rho = (const float*)d_in[5];
  const float* eps_hh  = (const float*)d_in[6];
  const float* b_mu    = (const float*)d_in[7];
  const float* b_rho   = (const float*)d_in[8];
  const float* eps_b   = (const float*)d_in[9];
  const float* fc_w    = (const float*)d_in[10];
  const float* fc_b    = (const float*)d_in[11];

  // ws layout: wpack [0, 2490368) | hbuf [2490368, +786432)
  //            xpack [3276800, +25165824)  (only if ws_size allows)
  unsigned short* wpack = (unsigned short*)d_ws;
  char* hbuf = (char*)d_ws + 2490368;
  unsigned short* xpack = (unsigned short*)((char*)d_ws + 3276800);
  const bool use_xpack = (ws_size >= 3276800ull + 25165824ull);

  // Clear ALL stamps each launch (replay safety): tag 0xFFFF matches no step.
  hipMemsetAsync(hbuf, 0xFF, 2 * NGRP * 16 * CH_STRIDE, stream);
  pack_w_kernel<<<NJ * 8 * NKK, 64, 0, stream>>>(wih_mu, wih_rho, eps_ih,
                                                 whh_mu, whh_rho, eps_hh, wpack);
  if (use_xpack) {
    pack_x_kernel<<<T_STEPS * 8, 64, 0, stream>>>(x, xpack);
    lstm_scan_kernel<true><<<NGRP * NJ, 256, 0, stream>>>(
        x, wpack, xpack, b_mu, b_rho, eps_b, fc_w, fc_b, hbuf, (float*)d_out);
  } else {
    lstm_scan_kernel<false><<<NGRP * NJ, 256, 0, stream>>>(
        x, wpack, (const unsigned short*)nullptr, b_mu, b_rho, eps_b,
        fc_w, fc_b, hbuf, (float*)d_out);
  }
}